// Round 2
// baseline (4380.733 us; speedup 1.0000x reference)
//
#include <hip/hip_runtime.h>
#include <hip/hip_cooperative_groups.h>
#include <math.h>

namespace cg = cooperative_groups;

#define BB 8
#define CC 256
#define NN 16384
#define NBVEC 16
#define NBLK 512           // BB * 64 chunks; each block owns 256 consecutive n
#define CHUNK 256

// ---------------- workspace layout (bytes) ----------------
// wsum   double[BB][CC]   @ 0      : 16384   (atomic-accumulated, zeroed each iter)
// sumSim double[BB]       @ 16384  : 64
// rv     float [BB][CC]   @ 16448  : 8192
// blkval double[NBLK]     @ 24640  : 4096    (per-block argmax value)
// blkidx int   [NBLK]     @ 28736  : 2048    (per-block argmax index, global n)

__global__ void __launch_bounds__(256, 2)
neighsim_coop_kernel(const float* __restrict__ x, float* __restrict__ out,
                     double* __restrict__ wsum, double* __restrict__ sumSim,
                     float* __restrict__ rv,
                     double* __restrict__ blkval, int* __restrict__ blkidx)
{
    cg::grid_group grid = cg::this_grid();
    const int t   = threadIdx.x;
    const int blk = blockIdx.x;
    const int b   = blk >> 6;          // batch
    const int n0  = (blk & 63) << 8;   // chunk base
    const int n   = n0 + t;            // this thread's spatial index (persistent)

    float* out_repr   = out;                                         // [NB][B][C]
    float* out_sims   = out + NBVEC*BB*CC;                           // [NB][B][N]
    float* out_selpos = out + NBVEC*BB*CC + (size_t)NBVEC*BB*NN;     // [B][N]

    const float* xb = x + (size_t)b*CC*NN;

    __shared__ float  s_rv[CC];
    __shared__ double s_sim[CHUNK];
    __shared__ double s_val[256];
    __shared__ int    s_idx[256];

    // ---- init: zero selpos (with the i==0 selection at N/2 baked in),
    //      zero wsum/sumSim, gather rv for i==0 (deterministic center pick).
    //      prior input is dead code (overwritten at i==0 in the reference).
    {
        int g = blk*256 + t;                       // [0, B*N)
        out_selpos[g] = ((g & (NN-1)) == NN/2) ? 1.0f : 0.0f;
    }
    if (blk < BB) {                                // blk == batch here
        wsum[blk*CC + t] = 0.0;
        if (t == 0) sumSim[blk] = 0.0;
        rv[blk*CC + t] = x[(size_t)blk*CC*NN + (size_t)t*NN + NN/2];
    }
    __threadfence();
    grid.sync();

    double score = 0.0;                            // this thread's score[n]

    for (int i = 0; i < NBVEC; ++i) {
        // ================= phase A (all 512 blocks) =================
        s_rv[t] = rv[b*CC + t];
        __syncthreads();

        // d^2 = sum_c (x - rv)^2 in fp64, same op order as round-1 (passed)
        double acc = 0.0;
        #pragma unroll 8
        for (int c = 0; c < CC; ++c) {
            double diff = (double)xb[(size_t)c*NN + n] - (double)s_rv[c];
            acc = fma(diff, diff, acc);
        }
        double d   = sqrt(acc + 1e-12);
        double sim = exp(-(d / 20.0));

        out_sims[(size_t)i*BB*NN + (size_t)b*NN + n] = (float)sim;
        score = (i == 0) ? (1.0 - sim) : (1.0 - sim) * score;
        s_sim[t] = sim;

        // block partial sumSim -> one fp64 atomic per block
        s_val[t] = sim;
        __syncthreads();
        for (int s = 128; s > 0; s >>= 1) {
            if (t < s) s_val[t] += s_val[t+s];
            __syncthreads();
        }
        if (t == 0) atomicAdd(&sumSim[b], s_val[0]);
        __syncthreads();                       // s_val about to be reused

        // block argmax of updated score (first-occurrence: lower n wins ties)
        s_val[t] = score; s_idx[t] = n;
        __syncthreads();
        for (int s = 128; s > 0; s >>= 1) {
            if (t < s) {
                double v2 = s_val[t+s]; int i2 = s_idx[t+s];
                if (v2 > s_val[t] || (v2 == s_val[t] && i2 < s_idx[t])) {
                    s_val[t] = v2; s_idx[t] = i2;
                }
            }
            __syncthreads();
        }
        if (t == 0) { blkval[blk] = s_val[0]; blkidx[blk] = s_idx[0]; }

        // phase-2 fused: thread t == channel c; wsum[b][c] += sum_{n in chunk} sim*x
        {
            const float4* xr4 = (const float4*)(xb + (size_t)t*NN + n0);
            double acc2 = 0.0;
            #pragma unroll 4
            for (int j4 = 0; j4 < CHUNK/4; ++j4) {
                float4 v = xr4[j4];
                int j = j4 * 4;
                acc2 = fma(s_sim[j+0], (double)v.x, acc2);
                acc2 = fma(s_sim[j+1], (double)v.y, acc2);
                acc2 = fma(s_sim[j+2], (double)v.z, acc2);
                acc2 = fma(s_sim[j+3], (double)v.w, acc2);
            }
            atomicAdd(&wsum[b*CC + t], acc2);
        }

        __threadfence();
        grid.sync();

        // ================= phase B (control; blocks 0..7, b == blk) ========
        if (blk < BB) {
            const int cb = blk;
            double ss = sumSim[cb];
            out_repr[(size_t)i*BB*CC + cb*CC + t] = (float)(wsum[cb*CC + t] / ss);
            wsum[cb*CC + t] = 0.0;
            if (t == 0) sumSim[cb] = 0.0;

            if (i < NBVEC-1) {
                // argmax across the 64 per-block results of this batch
                if (t < 64) { s_val[t] = blkval[cb*64 + t]; s_idx[t] = blkidx[cb*64 + t]; }
                else        { s_val[t] = -1.0e300;          s_idx[t] = 0x7fffffff; }
                __syncthreads();
                for (int s = 128; s > 0; s >>= 1) {
                    if (t < s) {
                        double v2 = s_val[t+s]; int i2 = s_idx[t+s];
                        if (v2 > s_val[t] || (v2 == s_val[t] && i2 < s_idx[t])) {
                            s_val[t] = v2; s_idx[t] = i2;
                        }
                    }
                    __syncthreads();
                }
                const int sel = s_idx[0];
                if (t == 0) out_selpos[cb*NN + sel] += 1.0f;
                rv[cb*CC + t] = x[(size_t)cb*CC*NN + (size_t)t*NN + sel];
            }
        }
        __threadfence();
        grid.sync();
    }
}

extern "C" void kernel_launch(void* const* d_in, const int* in_sizes, int n_in,
                              void* d_out, int out_size, void* d_ws, size_t ws_size,
                              hipStream_t stream)
{
    const float* x = (const float*)d_in[0];
    // d_in[1] (prior) provably unused; d_in[2] (nbVec) fixed at 16.
    float* out = (float*)d_out;

    char* ws = (char*)d_ws;
    double* wsum   = (double*)(ws);
    double* sumSim = (double*)(ws + 16384);
    float*  rv     = (float*) (ws + 16448);
    double* blkval = (double*)(ws + 24640);
    int*    blkidx = (int*)   (ws + 28736);

    void* args[] = { (void*)&x, (void*)&out, (void*)&wsum, (void*)&sumSim,
                     (void*)&rv, (void*)&blkval, (void*)&blkidx };
    hipLaunchCooperativeKernel((void*)neighsim_coop_kernel,
                               dim3(NBLK), dim3(256), args, 0, stream);
}

// Round 3
// 2620.530 us; speedup vs baseline: 1.6717x; 1.6717x over previous
//
#include <hip/hip_runtime.h>
#include <hip/hip_cooperative_groups.h>
#include <math.h>

namespace cg = cooperative_groups;

#define BB 8
#define CC 256
#define NN 16384
#define NBVEC 16
#define NBLK 256          // 1 block per CU (cooperative, 138 KB LDS)
#define COLS 512          // spatial columns owned per block (8*16384/256)
#define TCOLS 128         // columns per LDS tile
#define NT 4              // tiles per block per iteration
#define PAD 132           // padded tile row stride in words (16B-aligned rows)

// ---- workspace (bytes) ----
// wsum   double[NBVEC][BB][CC] @ 0      : 262144  (per-iter slices: no reset races)
// sumSim double[NBVEC][BB]     @ 262144 : 1024
// blkval double[NBVEC][NBLK]   @ 263168 : 32768
// blkidx int   [NBVEC][NBLK]   @ 295936 : 16384
//
// dynamic LDS (141312 B):
//  s_sim d[128] | s_part d[128] | s_val d[256] | s_idx i[256] | s_rv f[256]
//  | tile f[256*132]

__global__ void __launch_bounds__(256, 1)
neighsim_onepass(const float* __restrict__ x, float* __restrict__ out,
                 double* __restrict__ wsum, double* __restrict__ sumSim,
                 double* __restrict__ blkval, int* __restrict__ blkidx)
{
    cg::grid_group grid = cg::this_grid();
    extern __shared__ char smem[];
    double* s_sim  = (double*)smem;              // [128]
    double* s_part = s_sim + 128;                // [128]
    double* s_val  = s_part + 128;               // [256]
    int*    s_idx  = (int*)(s_val + 256);        // [256]
    float*  s_rv   = (float*)(s_idx + 256);      // [256]
    float*  tile   = s_rv + 256;                 // [256*PAD], base offset 6144 (16B ok)

    const int t     = threadIdx.x;
    const int blk   = blockIdx.x;
    const int b     = blk >> 5;                  // batch (32 blocks per batch)
    const int nbase = (blk & 31) * COLS;         // this block's column range
    const float* xb = x + (size_t)b*CC*NN;

    float* out_repr   = out;                                        // [NB][B][C]
    float* out_sims   = out + NBVEC*BB*CC;                          // [NB][B][N]
    float* out_selpos = out + NBVEC*BB*CC + (size_t)NBVEC*BB*NN;    // [B][N]

    // ---------- preamble: zero ws slices, init selpos (center pick baked in),
    //            gather rv for i==0 (prior input is dead code in the reference)
    {
        int g = blk*256 + t;                       // [0, 65536)
        if (g < NBVEC*BB*CC) wsum[g] = 0.0;
        if (g < NBVEC*BB)    sumSim[g] = 0.0;
        out_selpos[g]         = ((g & (NN-1)) == NN/2) ? 1.0f : 0.0f;
        int g2 = g + NBLK*256;
        out_selpos[g2]        = ((g2 & (NN-1)) == NN/2) ? 1.0f : 0.0f;
    }
    s_rv[t] = xb[(size_t)t*NN + NN/2];

    // ---------- register prefetch buffer: 32 float4 = one 128-col tile slice/thread
    const int srow = t >> 5;                 // 0..7 : row group
    const int scol = (t & 31) * 4;           // float4 column within tile
    float4 buf[32];

    auto issue_loads = [&](int tau) {
        const float* gp = xb + nbase + tau*TCOLS + scol;
        #pragma unroll
        for (int r = 0; r < 32; ++r)
            buf[r] = *(const float4*)(gp + (size_t)(r*8 + srow)*NN);   // coalesced 512B segs
    };
    auto write_tile = [&]() {
        #pragma unroll
        for (int r = 0; r < 32; ++r)
            *(float4*)&tile[(r*8 + srow)*PAD + scol] = buf[r];
    };

    issue_loads(0);
    __threadfence();
    grid.sync();

    const int jcol  = t & 127;               // column within tile (phase A)
    const int chalf = t >> 7;                // which channel half this thread sums
    double score[NT];                        // t<128: scores of its 4 owned columns

    for (int i = 0; i < NBVEC; ++i) {
        double wacc = 0.0;                   // phase-2 accumulator (c == t)
        double ssum = 0.0;                   // partial sum of sim (t<128)

        for (int tau = 0; tau < NT; ++tau) {
            __syncthreads();                 // (a) all done reading previous tile/s_sim
            write_tile();                    // drains vmcnt for tile tau
            issue_loads((tau+1) & 3);        // prefetch next (wraps: next iter reuses 0)
            __syncthreads();                 // (b) tile tau visible

            // ---- phase A: d^2 partial over this thread's channel half (fp64)
            const int c0 = chalf * 128;
            double a0 = 0.0, a1 = 0.0;
            #pragma unroll 16
            for (int c = 0; c < 128; c += 2) {
                double d0 = (double)tile[(c0+c  )*PAD + jcol] - (double)s_rv[c0+c];
                double d1 = (double)tile[(c0+c+1)*PAD + jcol] - (double)s_rv[c0+c+1];
                a0 = fma(d0, d0, a0);
                a1 = fma(d1, d1, a1);
            }
            double accp = a0 + a1;
            if (t >= 128) s_part[jcol] = accp;
            __syncthreads();                 // (c)
            if (t < 128) {
                double d2  = accp + s_part[jcol];
                double d   = sqrt(d2 + 1e-12);
                double sim = exp(-(d / 20.0));
                s_sim[jcol] = sim;
                out_sims[(size_t)i*BB*NN + (size_t)b*NN + nbase + tau*TCOLS + jcol]
                    = (float)sim;
                score[tau] = (i == 0) ? (1.0 - sim) : (1.0 - sim) * score[tau];
                ssum += sim;
            }
            __syncthreads();                 // (d) s_sim ready

            // ---- phase 2: wsum partial, c == t, b128 LDS reads (bank-balanced)
            double w0 = 0.0, w1 = 0.0;
            #pragma unroll 8
            for (int j4 = 0; j4 < 32; j4 += 2) {
                float4 v0 = *(float4*)&tile[t*PAD + 4*j4];
                float4 v1 = *(float4*)&tile[t*PAD + 4*j4 + 4];
                int j = 4*j4;
                w0 = fma(s_sim[j+0], (double)v0.x, w0);
                w0 = fma(s_sim[j+1], (double)v0.y, w0);
                w0 = fma(s_sim[j+2], (double)v0.z, w0);
                w0 = fma(s_sim[j+3], (double)v0.w, w0);
                w1 = fma(s_sim[j+4], (double)v1.x, w1);
                w1 = fma(s_sim[j+5], (double)v1.y, w1);
                w1 = fma(s_sim[j+6], (double)v1.z, w1);
                w1 = fma(s_sim[j+7], (double)v1.w, w1);
            }
            wacc += w0 + w1;
        }

        atomicAdd(&wsum[(size_t)(i*BB + b)*CC + t], wacc);

        // ---- block reduce sumSim
        s_val[t] = ssum;
        __syncthreads();
        for (int s = 128; s > 0; s >>= 1) {
            if (t < s) s_val[t] += s_val[t+s];
            __syncthreads();
        }
        if (t == 0) atomicAdd(&sumSim[i*BB + b], s_val[0]);
        __syncthreads();

        // ---- block argmax of score (first-occurrence: lower n wins ties)
        double bv = -1.0e300; int bi = 0x7fffffff;
        if (t < 128) {
            #pragma unroll
            for (int tau = 0; tau < NT; ++tau) {
                double v = score[tau];
                int    n = nbase + tau*TCOLS + t;
                if (v > bv) { bv = v; bi = n; }    // ascending n per thread
            }
        }
        s_val[t] = bv; s_idx[t] = bi;
        __syncthreads();
        for (int s = 128; s > 0; s >>= 1) {
            if (t < s) {
                double v2 = s_val[t+s]; int i2 = s_idx[t+s];
                if (v2 > s_val[t] || (v2 == s_val[t] && i2 < s_idx[t])) {
                    s_val[t] = v2; s_idx[t] = i2;
                }
            }
            __syncthreads();
        }
        if (t == 0) { blkval[i*NBLK + blk] = s_val[0]; blkidx[i*NBLK + blk] = s_idx[0]; }

        __threadfence();
        grid.sync();                          // the ONLY grid sync per iteration

        // ---- control, replicated per block for its own batch
        if (t < 32) {
            s_val[t] = blkval[i*NBLK + b*32 + t];
            s_idx[t] = blkidx[i*NBLK + b*32 + t];
        }
        __syncthreads();
        for (int s = 16; s > 0; s >>= 1) {
            if (t < s) {
                double v2 = s_val[t+s]; int i2 = s_idx[t+s];
                if (v2 > s_val[t] || (v2 == s_val[t] && i2 < s_idx[t])) {
                    s_val[t] = v2; s_idx[t] = i2;
                }
            }
            __syncthreads();
        }
        const int sel = s_idx[0];

        if ((blk & 31) == 0) {                // one writer block per batch
            double ss = sumSim[i*BB + b];
            out_repr[(size_t)i*BB*CC + b*CC + t] =
                (float)(wsum[(size_t)(i*BB + b)*CC + t] / ss);
            if (t == 0 && i < NBVEC-1) out_selpos[b*NN + sel] += 1.0f;
        }
        if (i < NBVEC-1) s_rv[t] = xb[(size_t)t*NN + sel];
        // next tile-loop's sync (a) makes s_rv visible
    }
}

extern "C" void kernel_launch(void* const* d_in, const int* in_sizes, int n_in,
                              void* d_out, int out_size, void* d_ws, size_t ws_size,
                              hipStream_t stream)
{
    const float* x = (const float*)d_in[0];
    // d_in[1] (prior) provably unused; d_in[2] (nbVec) fixed at 16.
    float* out = (float*)d_out;

    char* ws = (char*)d_ws;
    double* wsum   = (double*)(ws);
    double* sumSim = (double*)(ws + 262144);
    double* blkval = (double*)(ws + 263168);
    int*    blkidx = (int*)   (ws + 295936);

    const int smem_bytes = 141312;   // 6144 control + 256*132*4 tile
    hipFuncSetAttribute((const void*)neighsim_onepass,
                        hipFuncAttributeMaxDynamicSharedMemorySize, smem_bytes);

    void* args[] = { (void*)&x, (void*)&out, (void*)&wsum, (void*)&sumSim,
                     (void*)&blkval, (void*)&blkidx };
    hipLaunchCooperativeKernel((void*)neighsim_onepass,
                               dim3(NBLK), dim3(256), args, smem_bytes, stream);
}